// Round 1
// baseline (412.136 us; speedup 1.0000x reference)
//
#include <hip/hip_runtime.h>
#include <math.h>

#define IMGN 32
#define HT 1024
#define WD 1024
#define IMG_STRIDE (HT*WD)
#define NTOT (IMGN*HT*WD)
#define LOSS_THR_F 120.0f

// order-preserving float<->uint maps for atomic min/max
__device__ __forceinline__ unsigned f2ord(float f){
  unsigned u = __float_as_uint(f);
  return (u & 0x80000000u) ? ~u : (u | 0x80000000u);
}
__device__ __forceinline__ float ord2f(unsigned v){
  unsigned u = (v & 0x80000000u) ? (v ^ 0x80000000u) : ~v;
  return __uint_as_float(u);
}

__global__ void k_init(unsigned* ws){
  if (threadIdx.x == 0){ ws[0] = 0xFFFFFFFFu; ws[1] = 0u; }
}

// global min/max over xd (width deltas, col 0 delta = x itself)
__global__ __launch_bounds__(256) void k_minmax(const float* __restrict__ x,
                                                unsigned* __restrict__ ws){
  const int NF4 = NTOT/4;
  int gid = blockIdx.x*256 + threadIdx.x;
  int nth = gridDim.x*256;
  float lmin = INFINITY, lmax = -INFINITY;
  const float4* x4 = (const float4*)x;
  for (int g = gid; g < NF4; g += nth){
    float4 v = x4[g];
    float prevw = __shfl_up(v.w, 1);
    int col4 = g & 255;           // float4 index within a 1024-wide row
    float left;
    if (col4 == 0) left = 0.0f;   // delta = x - 0
    else if ((threadIdx.x & 63) == 0) left = x[(size_t)g*4 - 1];
    else left = prevw;            // consecutive lanes hold consecutive g
    float d0 = v.x - left, d1 = v.y - v.x, d2 = v.z - v.y, d3 = v.w - v.z;
    lmin = fminf(lmin, fminf(fminf(d0, d1), fminf(d2, d3)));
    lmax = fmaxf(lmax, fmaxf(fmaxf(d0, d1), fmaxf(d2, d3)));
  }
  #pragma unroll
  for (int off = 32; off; off >>= 1){
    lmin = fminf(lmin, __shfl_xor(lmin, off));
    lmax = fmaxf(lmax, __shfl_xor(lmax, off));
  }
  __shared__ float smin[4], smax[4];
  int wv = threadIdx.x >> 6;
  if ((threadIdx.x & 63) == 0){ smin[wv] = lmin; smax[wv] = lmax; }
  __syncthreads();
  if (threadIdx.x == 0){
    float bmin = fminf(fminf(smin[0], smin[1]), fminf(smin[2], smin[3]));
    float bmax = fmaxf(fmaxf(smax[0], smax[1]), fmaxf(smax[2], smax[3]));
    atomicMin(&ws[0], f2ord(bmin));
    atomicMax(&ws[1], f2ord(bmax));
  }
}

// one 256-thread workgroup per 8x8 spatial block (128x128 blocks)
__global__ __launch_bounds__(256) void k_main(const float* __restrict__ x,
                                              float* __restrict__ out,
                                              const unsigned* __restrict__ ws){
  // transposed [p][i] layout, stride 33: every access pattern <=2-way bank alias
  __shared__ float xmain[64*33];
  __shared__ float dsh[64*33];
  __shared__ float xleft[256];
  __shared__ float s_inv[9];
  __shared__ int   s_degen;

  const int tid = threadIdx.x;
  const int bid = blockIdx.x;
  const int wb = bid & 127;
  const int hb = bid >> 7;
  const int row0 = hb << 3;
  const int col0 = wb << 3;

  const float mn = ord2f(ws[0]);
  const float mx = ord2f(ws[1]);
  const bool  neq = (mx != mn);
  const float scale = neq ? (65535.0f / (mx - mn)) : 1.0f;
  const float sinv  = 1.0f / scale;
  const float moff  = neq ? mn : 0.0f;
  // part_quant1: lsb = 2 ** (round(log2(mx / 2^15)) + 1)
  const float lsb = exp2f(rintf(log2f(mx / 32768.0f)) + 1.0f);

  // ---- stage x tile (8 rows x 8 cols x 32 images) into LDS, float4 loads
  const float4* x4 = (const float4*)x;
  #pragma unroll
  for (int k = 0; k < 2; ++k){
    int f = tid + (k << 8);          // 0..511 float4s
    int i = f >> 4;
    int rem = f & 15;
    int hh = rem >> 1;
    int half = rem & 1;
    float4 v = x4[(size_t)i*(IMG_STRIDE/4) + (size_t)(row0+hh)*(WD/4) + (col0>>2) + half];
    int pbase = (hh << 3) + (half << 2);
    xmain[(pbase+0)*33 + i] = v.x;
    xmain[(pbase+1)*33 + i] = v.y;
    xmain[(pbase+2)*33 + i] = v.z;
    xmain[(pbase+3)*33 + i] = v.w;
  }
  {
    int i = tid >> 3, hh = tid & 7;
    xleft[tid] = (wb == 0) ? 0.0f
               : x[(size_t)i*IMG_STRIDE + (size_t)(row0+hh)*WD + col0 - 1];
  }
  __syncthreads();

  // ---- quantize/dequantize deltas -> dsh  (x1 in reference)
  #pragma unroll
  for (int k = 0; k < 8; ++k){
    int e = tid + (k << 8);
    int i = e >> 6;                  // constant per wave
    int p = e & 63;                  // = lane
    float xm = xmain[p*33 + i];
    float xl = (p & 7) ? xmain[(p-1)*33 + i] : xleft[(i << 3) + (p >> 3)];
    float xd = xm - xl;
    float v;
    if (neq){
      float q = rintf((xd - mn) * scale);           // jnp.round = half-even
      v = __fadd_rn(__fmul_rn(q, sinv), moff);      // no FMA contraction
    } else v = xd;
    dsh[p*33 + i] = v;
  }
  __syncthreads();

  // ---- normal matrix AT_A (3x3) + degen flag: wave 0, one lane per pixel
  if (tid < 64){
    float a0 = dsh[tid*33 + 0];      // image 0 block (A row 0)
    float a1 = dsh[tid*33 + 1];      // image 1 block (A row 1)
    double s00 = (double)a0*a0, s01 = (double)a0*a1, s02 = a0;
    double s11 = (double)a1*a1, s12 = a1;
    float mx0 = a0, mn0 = a0, mx1 = a1, mn1 = a1;
    #pragma unroll
    for (int off = 32; off; off >>= 1){
      s00 += __shfl_xor(s00, off);
      s01 += __shfl_xor(s01, off);
      s02 += __shfl_xor(s02, off);
      s11 += __shfl_xor(s11, off);
      s12 += __shfl_xor(s12, off);
      mx0 = fmaxf(mx0, __shfl_xor(mx0, off));
      mn0 = fminf(mn0, __shfl_xor(mn0, off));
      mx1 = fmaxf(mx1, __shfl_xor(mx1, off));
      mn1 = fminf(mn1, __shfl_xor(mn1, off));
    }
    if (tid == 0){
      // round sums to f32 (reference AT_A is f32), invert in f64 (adjugate)
      double a = (float)s00, b = (float)s01, c = (float)s02;
      double d = (float)s11, e = (float)s12, f = 64.0;
      double c00 = d*f - e*e;
      double c01 = c*e - b*f;
      double c02 = b*e - c*d;
      double det = a*c00 + b*c01 + c*c02;
      float inv[9];
      if (det == 0.0){               // reference: AT_A <- eye, inv(eye)=eye
        inv[0]=1.f;inv[1]=0.f;inv[2]=0.f;
        inv[3]=0.f;inv[4]=1.f;inv[5]=0.f;
        inv[6]=0.f;inv[7]=0.f;inv[8]=1.f;
      } else {
        double id = 1.0/det;
        double c11 = a*f - c*c;
        double c12 = b*c - a*e;
        double c22 = a*d - b*b;
        inv[0]=(float)(c00*id); inv[1]=(float)(c01*id); inv[2]=(float)(c02*id);
        inv[3]=inv[1];          inv[4]=(float)(c11*id); inv[5]=(float)(c12*id);
        inv[6]=inv[2];          inv[7]=inv[5];          inv[8]=(float)(c22*id);
      }
      #pragma unroll
      for (int j = 0; j < 9; ++j) s_inv[j] = inv[j];
      s_degen = (((mx0 - mn0) < 1e-6f) && ((mx1 - mn1) < 1e-6f)) ? 1 : 0;
    }
  }
  __syncthreads();

  // ---- per-image fit: 8 threads per image, 8 pixels each
  const int i_img = tid >> 3;
  const int sub   = tid & 7;         // = hh of this thread's pixel row
  const int p0    = sub << 3;

  float dv[8], a0v[8], a1v[8];
  #pragma unroll
  for (int c2 = 0; c2 < 8; ++c2){
    int p = p0 + c2;
    dv[c2]  = dsh[p*33 + i_img];
    a0v[c2] = dsh[p*33 + 0];
    a1v[c2] = dsh[p*33 + 1];
  }
  const float i00 = s_inv[0], i01 = s_inv[1], i02 = s_inv[2];
  const float i10 = s_inv[3], i11 = s_inv[4], i12 = s_inv[5];
  const float i20 = s_inv[6], i21 = s_inv[7], i22 = s_inv[8];

  // p_coef = (inv @ A) @ d  for this image; base recomputed per element
  float pc0 = 0.f, pc1 = 0.f, pc2v = 0.f;
  #pragma unroll
  for (int c2 = 0; c2 < 8; ++c2){
    float b0 = __fadd_rn(__fmaf_rn(i01, a1v[c2], __fmul_rn(i00, a0v[c2])), i02);
    float b1 = __fadd_rn(__fmaf_rn(i11, a1v[c2], __fmul_rn(i10, a0v[c2])), i12);
    float b2 = __fadd_rn(__fmaf_rn(i21, a1v[c2], __fmul_rn(i20, a0v[c2])), i22);
    pc0  = __fmaf_rn(b0, dv[c2], pc0);
    pc1  = __fmaf_rn(b1, dv[c2], pc1);
    pc2v = __fmaf_rn(b2, dv[c2], pc2v);
  }
  pc0  += __shfl_xor(pc0, 1);  pc0  += __shfl_xor(pc0, 2);  pc0  += __shfl_xor(pc0, 4);
  pc1  += __shfl_xor(pc1, 1);  pc1  += __shfl_xor(pc1, 2);  pc1  += __shfl_xor(pc1, 4);
  pc2v += __shfl_xor(pc2v, 1); pc2v += __shfl_xor(pc2v, 2); pc2v += __shfl_xor(pc2v, 4);

  // reconstruction r = A^T @ p, quantize, loss
  const int degen = s_degen;
  float r1v[8];
  float loss = 0.f;
  #pragma unroll
  for (int c2 = 0; c2 < 8; ++c2){
    float r  = __fadd_rn(__fmaf_rn(a1v[c2], pc1, __fmul_rn(a0v[c2], pc0)), pc2v);
    float r1 = __fmul_rn(rintf(__fdiv_rn(r, lsb)), lsb);   // lsb is 2^k: exact
    r1v[c2] = r1;
    float df = __fsub_rn(dv[c2], r1);
    loss = __fadd_rn(loss, __fmul_rn(df, df));
  }
  loss += __shfl_xor(loss, 1); loss += __shfl_xor(loss, 2); loss += __shfl_xor(loss, 4);
  const bool sel = (!degen) && (loss <= LOSS_THR_F);

  // ---- select + un-delta + store (two aligned float4 per thread)
  size_t obase = (size_t)i_img*IMG_STRIDE + (size_t)(row0 + sub)*WD + col0;
  float o[8];
  #pragma unroll
  for (int c2 = 0; c2 < 8; ++c2){
    int p = p0 + c2;
    float xl = (c2 == 0) ? xleft[(i_img << 3) + sub] : xmain[(p-1)*33 + i_img];
    float rrv = sel ? r1v[c2] : dv[c2];
    o[c2] = rrv + xl;
  }
  *(float4*)(out + obase)     = make_float4(o[0], o[1], o[2], o[3]);
  *(float4*)(out + obase + 4) = make_float4(o[4], o[5], o[6], o[7]);
}

extern "C" void kernel_launch(void* const* d_in, const int* in_sizes, int n_in,
                              void* d_out, int out_size, void* d_ws, size_t ws_size,
                              hipStream_t stream) {
  const float* x = (const float*)d_in[0];
  float* out = (float*)d_out;
  unsigned* ws = (unsigned*)d_ws;
  hipLaunchKernelGGL(k_init,   dim3(1),     dim3(64),  0, stream, ws);
  hipLaunchKernelGGL(k_minmax, dim3(2048),  dim3(256), 0, stream, x, ws);
  hipLaunchKernelGGL(k_main,   dim3(16384), dim3(256), 0, stream, x, out, ws);
}